// Round 3
// baseline (333.198 us; speedup 1.0000x reference)
//
#include <hip/hip_runtime.h>
#include <hip/hip_bf16.h>
#include <math.h>

// Problem constants
#define TT   4096     // T
#define BB   16       // B
#define NTOK 65536    // B*T
#define CIN  512      // IN_FEATS
#define EF   256      // EMBED_FEATS
#define NE   1024     // NUM_EMBED

typedef __attribute__((ext_vector_type(8))) short bf16x8;
typedef __attribute__((ext_vector_type(4))) float f32x4;

static __device__ __forceinline__ unsigned short f2bf(float f) {
  unsigned int u = __float_as_uint(f);
  u += 0x7fffu + ((u >> 16) & 1u);          // RNE
  return (unsigned short)(u >> 16);
}

// async global->LDS, 16B per lane; LDS dest is wave-uniform base + lane*16
#define GLL(gsrc, ldst) \
  __builtin_amdgcn_global_load_lds((const __attribute__((address_space(1))) void*)(gsrc), \
                                   (__attribute__((address_space(3))) void*)(ldst), 16, 0, 0)

// ---------------------------------------------------------------------------
// K0: convert proj_w -> bf16; embed -> bf16*(-2); e_norm[k] = ||embed_k||^2
// ---------------------------------------------------------------------------
__global__ __launch_bounds__(256) void k_prep(const float* __restrict__ Wf,
                                              const float* __restrict__ Ef,
                                              unsigned short* __restrict__ Wbf,
                                              unsigned short* __restrict__ Ebf,
                                              float* __restrict__ e_norm) {
  int bid = blockIdx.x;
  if (bid < 512) {                      // W: 256*512 = 131072 elems
    int i = bid * 256 + threadIdx.x;
    Wbf[i] = f2bf(Wf[i]);
  } else if (bid < 1536) {              // E scaled by -2 (exact): 262144 elems
    int i = (bid - 512) * 256 + threadIdx.x;
    Ebf[i] = f2bf(-2.0f * Ef[i]);
  } else {                              // e_norm: 256 blocks * 4 codes (1 wave/code)
    int w = threadIdx.x >> 6, l = threadIdx.x & 63;
    int k = (bid - 1536) * 4 + w;
    const float4 v4 = ((const float4*)(Ef + (size_t)k * EF))[l];
    float s = v4.x * v4.x + v4.y * v4.y + v4.z * v4.z + v4.w * v4.w;
    for (int off = 32; off; off >>= 1) s += __shfl_down(s, off);
    if (l == 0) e_norm[k] = s;
  }
}

// ---------------------------------------------------------------------------
// K1 (fused): per 64-token block:
//  phase1: x = in^T @ W^T (A transposed+converted in regs -> swizzled LDS;
//          W via global_load_lds). acc[4][4].
//  phase2: x += bias -> bf16 into LDS xs[64][256]; xsq += x^2
//  phase3: dist = ||e||^2 - 2 x.e ; 8 chunks of 128 codes (32 codes/wave,
//          dacc[4][2] = 32 VGPRs -- keeps peak live set < 128, NO SPILLS)
//  phase4: argmin merge -> bi, hist, sse += sum(best_v) + sum(x^2)
// LDS 48 KB: phase1 as[64][64]@0 (8K) bs[256][64]@8K (32K);
//            phase2/3 xs[64][256]@0 (32K) es[128][64]@32K (16K)
// => 3 blocks/CU if VGPR<=128
// ---------------------------------------------------------------------------
__global__ __launch_bounds__(256, 2) void k_fused(const float* __restrict__ in,
                                                  const unsigned short* __restrict__ Wbf,
                                                  const float* __restrict__ bias,
                                                  const unsigned short* __restrict__ Ebf,
                                                  const float* __restrict__ e_norm,
                                                  int* __restrict__ bi_out,
                                                  unsigned int* __restrict__ hist,
                                                  float* __restrict__ sse) {
  __shared__ unsigned short lds[24576];  // 48 KB
  unsigned short* as_ = lds;            // phase1 A tile [64 t][64 c]
  unsigned short* bs = lds + 4096;      // phase1 W tile [256 e][64 c]
  unsigned short* xs = lds;             // phase2/3 x tile [64 t][256 e]
  unsigned short* es = lds + 16384;     // phase3 embed tile [128 code][64 e]

  int tid = threadIdx.x;
  int w = tid >> 6, l = tid & 63;
  int l15 = l & 15, quad = l >> 4;
  int tok0 = blockIdx.x * 64;
  int bidx = tok0 >> 12;
  int tg0 = tok0 & 4095;
  const float* src = in + (size_t)bidx * CIN * TT + tg0;

  // ------------------ phase 1: projection GEMM ------------------
  f32x4 acc[4][4];
#pragma unroll
  for (int a = 0; a < 4; ++a)
#pragma unroll
    for (int b = 0; b < 4; ++b) acc[a][b] = (f32x4){0.f, 0.f, 0.f, 0.f};

  for (int ks = 0; ks < 8; ++ks) {
    int k0 = ks * 64;
    // W: async global->LDS (2048 16B chunks)
#pragma unroll
    for (int i = 0; i < 8; ++i) {
      int g = i * 256 + tid;
      int row = g >> 3, pc = g & 7, lc = pc ^ (row & 7);
      GLL(Wbf + (size_t)row * CIN + k0 + lc * 8, bs + g * 8);
    }
    // A: transposed loads (lane over t), 8 c at a time to cap registers
#pragma unroll
    for (int cc = 0; cc < 2; ++cc) {
      float v[8];
      const float* s0 = src + (size_t)(k0 + w * 16 + cc * 8) * TT + l;
#pragma unroll
      for (int i = 0; i < 8; ++i) v[i] = s0[(size_t)i * TT];
      alignas(16) unsigned short tmp[8];
#pragma unroll
      for (int j = 0; j < 8; ++j) tmp[j] = f2bf(v[j]);
      int c8 = w * 2 + cc;
      int pc = c8 ^ (l & 7);
      *(bf16x8*)(as_ + l * 64 + pc * 8) = *(const bf16x8*)tmp;
    }
    __syncthreads();
#pragma unroll
    for (int s = 0; s < 2; ++s) {
      int lcb = s * 4 + quad;
      bf16x8 af[4], bfr[4];
#pragma unroll
      for (int msub = 0; msub < 4; ++msub) {
        int row = msub * 16 + l15;
        int pc = lcb ^ (row & 7);
        af[msub] = *(const bf16x8*)(as_ + row * 64 + pc * 8);
      }
#pragma unroll
      for (int nsub = 0; nsub < 4; ++nsub) {
        int row = w * 64 + nsub * 16 + l15;
        int pc = lcb ^ (row & 7);
        bfr[nsub] = *(const bf16x8*)(bs + row * 64 + pc * 8);
      }
#pragma unroll
      for (int msub = 0; msub < 4; ++msub)
#pragma unroll
        for (int nsub = 0; nsub < 4; ++nsub)
          acc[msub][nsub] = __builtin_amdgcn_mfma_f32_16x16x32_bf16(af[msub], bfr[nsub],
                                                                    acc[msub][nsub], 0, 0, 0);
    }
    __syncthreads();
  }

  // ------------------ phase 2: bias + x -> LDS xs, xsq ------------------
  float xsq = 0.f;
#pragma unroll
  for (int nsub = 0; nsub < 4; ++nsub) {
    float bv = bias[w * 64 + nsub * 16 + l15];
    int e = w * 64 + nsub * 16 + l15;
    int cx = e >> 3;
#pragma unroll
    for (int msub = 0; msub < 4; ++msub)
#pragma unroll
      for (int reg = 0; reg < 4; ++reg) {
        int m = msub * 16 + quad * 4 + reg;
        float x = acc[msub][nsub][reg] + bv;
        xsq += x * x;
        int pcx = cx ^ (m & 31);
        xs[m * 256 + pcx * 8 + (e & 7)] = f2bf(x);
      }
  }
  __syncthreads();

  // ------------------ phase 3: distances + running argmin ------------------
  float best_v[4][4];
  int best_i[4][4];
#pragma unroll
  for (int a = 0; a < 4; ++a)
#pragma unroll
    for (int b = 0; b < 4; ++b) { best_v[a][b] = 3.0e38f; best_i[a][b] = 0; }

  for (int chunk = 0; chunk < 8; ++chunk) {
    int c0 = chunk * 128;
    f32x4 dacc[4][2];
#pragma unroll
    for (int nsub = 0; nsub < 2; ++nsub) {
      float en = e_norm[c0 + w * 32 + nsub * 16 + l15];
#pragma unroll
      for (int msub = 0; msub < 4; ++msub) dacc[msub][nsub] = (f32x4){en, en, en, en};
    }
    for (int ks = 0; ks < 4; ++ks) {
      int k0 = ks * 64;
#pragma unroll
      for (int i = 0; i < 4; ++i) {     // stage es: 1024 16B chunks
        int g = i * 256 + tid;
        int row = g >> 3, pc = g & 7, lc = pc ^ (row & 7);
        GLL(Ebf + (size_t)(c0 + row) * EF + k0 + lc * 8, es + g * 8);
      }
      __syncthreads();
#pragma unroll
      for (int s = 0; s < 2; ++s) {
        bf16x8 af[4], bfr[2];
        int cx = ks * 8 + s * 4 + quad;   // k-chunk within xs row (0..31)
#pragma unroll
        for (int msub = 0; msub < 4; ++msub) {
          int row = msub * 16 + l15;
          int pcx = cx ^ (row & 31);
          af[msub] = *(const bf16x8*)(xs + row * 256 + pcx * 8);
        }
        int ck = s * 4 + quad;            // k-chunk within es row (0..7)
#pragma unroll
        for (int nsub = 0; nsub < 2; ++nsub) {
          int row = w * 32 + nsub * 16 + l15;
          int pc = ck ^ (row & 7);
          bfr[nsub] = *(const bf16x8*)(es + row * 64 + pc * 8);
        }
#pragma unroll
        for (int msub = 0; msub < 4; ++msub)
#pragma unroll
          for (int nsub = 0; nsub < 2; ++nsub)
            dacc[msub][nsub] = __builtin_amdgcn_mfma_f32_16x16x32_bf16(af[msub], bfr[nsub],
                                                                       dacc[msub][nsub], 0, 0, 0);
      }
      __syncthreads();
    }
#pragma unroll
    for (int msub = 0; msub < 4; ++msub)
#pragma unroll
      for (int nsub = 0; nsub < 2; ++nsub) {
        int code = c0 + w * 32 + nsub * 16 + l15;
#pragma unroll
        for (int reg = 0; reg < 4; ++reg) {
          float v = dacc[msub][nsub][reg];
          if (v < best_v[msub][reg]) { best_v[msub][reg] = v; best_i[msub][reg] = code; }
        }
      }
  }

  // ------------------ phase 4: argmin merge, outputs ------------------
#pragma unroll
  for (int msub = 0; msub < 4; ++msub)
#pragma unroll
    for (int reg = 0; reg < 4; ++reg) {
      float v = best_v[msub][reg];
      int idx = best_i[msub][reg];
#pragma unroll
      for (int off = 8; off; off >>= 1) {
        float ov = __shfl_xor(v, off, 16);
        int oi = __shfl_xor(idx, off, 16);
        if (ov < v || (ov == v && oi < idx)) { v = ov; idx = oi; }
      }
      best_v[msub][reg] = v;
      best_i[msub][reg] = idx;
    }
  float* red_v = (float*)es;         // [4][64]
  int* red_i = (int*)(es) + 256;     // [4][64]
  float* xred = (float*)(es) + 512;  // [4]
  if (l15 == 0) {
#pragma unroll
    for (int msub = 0; msub < 4; ++msub)
#pragma unroll
      for (int reg = 0; reg < 4; ++reg) {
        int m = msub * 16 + quad * 4 + reg;
        red_v[w * 64 + m] = best_v[msub][reg];
        red_i[w * 64 + m] = best_i[msub][reg];
      }
  }
  for (int off = 32; off; off >>= 1) xsq += __shfl_down(xsq, off);
  if (l == 0) xred[w] = xsq;
  __syncthreads();
  if (tid < 64) {
    float v = red_v[tid];
    int idx = red_i[tid];
#pragma unroll
    for (int wj = 1; wj < 4; ++wj) {
      float ov = red_v[wj * 64 + tid];
      int oi = red_i[wj * 64 + tid];
      if (ov < v || (ov == v && oi < idx)) { v = ov; idx = oi; }
    }
    bi_out[tok0 + tid] = idx;
    atomicAdd(&hist[idx], 1u);
    float sv = v;
    for (int off = 32; off; off >>= 1) sv += __shfl_down(sv, off);
    if (tid == 0) atomicAdd(sse, sv + xred[0] + xred[1] + xred[2] + xred[3]);
  }
}

// ---------------------------------------------------------------------------
// K2: gather embed rows (fp32 exact) by final index, write z_q transposed
// [B][EF][TT]. Tile: 128 tokens x 64 e. LDS [t][e] stride 65 (~2-way max
// banks both phases); f4 global reads (256B/row) and f4 global writes
// (512B contiguous per e-row).
// ---------------------------------------------------------------------------
__global__ __launch_bounds__(256) void k_gather(const float* __restrict__ embed,
                                                const int* __restrict__ bi,
                                                float* __restrict__ out) {
  __shared__ float zq[128 * 65];
  __shared__ int idxs[128];
  int tid = threadIdx.x;
  int tok0 = blockIdx.x * 128;
  int e0 = blockIdx.y * 64;
  if (tid < 128) idxs[tid] = bi[tok0 + tid];
  __syncthreads();
  int l15 = tid & 15, tg = tid >> 4;   // 16 thread-groups of 16 lanes
  for (int r = 0; r < 8; ++r) {
    int tl = r * 16 + tg;
    const float4 v = *(const float4*)(embed + (size_t)idxs[tl] * EF + e0 + l15 * 4);
    float* zr = zq + tl * 65 + l15 * 4;
    zr[0] = v.x; zr[1] = v.y; zr[2] = v.z; zr[3] = v.w;
  }
  __syncthreads();
  int b = tok0 >> 12, t0 = tok0 & 4095;
  int tl4 = (tid & 31) * 4;
  for (int r = 0; r < 8; ++r) {
    int e = r * 8 + (tid >> 5);
    float4 v;
    v.x = zq[(tl4 + 0) * 65 + e];
    v.y = zq[(tl4 + 1) * 65 + e];
    v.z = zq[(tl4 + 2) * 65 + e];
    v.w = zq[(tl4 + 3) * 65 + e];
    *(float4*)(out + ((size_t)(b * EF + e0 + e) << 12) + t0 + tl4) = v;
  }
}

// ---------------------------------------------------------------------------
// K3: finalize scalars
// ---------------------------------------------------------------------------
__global__ __launch_bounds__(256) void k_final(const unsigned int* __restrict__ hist,
                                               const float* __restrict__ sse,
                                               float* __restrict__ out) {
  __shared__ float red[4];
  int tid = threadIdx.x;
  float local = 0.f;
  for (int i = tid; i < NE; i += 256) {
    float p = (float)hist[i] * (1.0f / 65536.0f);
    local -= p * logf(p + 1e-10f);
  }
  for (int off = 32; off; off >>= 1) local += __shfl_down(local, off);
  if ((tid & 63) == 0) red[tid >> 6] = local;
  __syncthreads();
  if (tid == 0) {
    float lp = red[0] + red[1] + red[2] + red[3];
    out[16777216] = 1.25f * sse[0] / 16777216.0f;  // vq + 0.25*commitment
    out[16777233] = lp;
  }
  if (tid < 16) out[16777217 + tid] = 6.93147180559945f * 4096.0f;  // log(1024)*4096
}

// ---------------------------------------------------------------------------
extern "C" void kernel_launch(void* const* d_in, const int* in_sizes, int n_in,
                              void* d_out, int out_size, void* d_ws, size_t ws_size,
                              hipStream_t stream) {
  const float* inputs = (const float*)d_in[0];
  const float* proj_w = (const float*)d_in[1];
  const float* proj_b = (const float*)d_in[2];
  const float* embed = (const float*)d_in[3];
  float* out = (float*)d_out;
  char* ws = (char*)d_ws;

  // workspace layout
  unsigned short* Wbf  = (unsigned short*)(ws);            //   262,144 B
  unsigned short* Ebf  = (unsigned short*)(ws + 262144);   //   524,288 B
  float* e_norm        = (float*)(ws + 786432);            //     4,096 B
  int* bi              = (int*)(ws + 790528);              //   262,144 B
  unsigned int* hist   = (unsigned int*)(ws + 1052672);    //     4,096 B
  float* sse           = (float*)(ws + 1056768);           //         4 B
  if (ws_size < 1056772) return;

  hipMemsetAsync(ws + 1052672, 0, 4100, stream);  // hist + sse

  k_prep<<<1792, 256, 0, stream>>>(proj_w, embed, Wbf, Ebf, e_norm);
  k_fused<<<1024, 256, 0, stream>>>(inputs, Wbf, proj_b, Ebf, e_norm, bi, hist, sse);
  k_gather<<<dim3(512, 4), 256, 0, stream>>>(embed, bi, out);
  k_final<<<1, 256, 0, stream>>>(hist, sse, out);
}

// Round 4
// 327.254 us; speedup vs baseline: 1.0182x; 1.0182x over previous
//
#include <hip/hip_runtime.h>
#include <hip/hip_bf16.h>
#include <math.h>

// Problem constants
#define TT   4096     // T
#define BB   16       // B
#define NTOK 65536    // B*T
#define CIN  512      // IN_FEATS
#define EF   256      // EMBED_FEATS
#define NE   1024     // NUM_EMBED

typedef __attribute__((ext_vector_type(8))) short bf16x8;
typedef __attribute__((ext_vector_type(4))) float f32x4;

static __device__ __forceinline__ unsigned short f2bf(float f) {
  unsigned int u = __float_as_uint(f);
  u += 0x7fffu + ((u >> 16) & 1u);          // RNE
  return (unsigned short)(u >> 16);
}

// async global->LDS, 16B per lane; LDS dest is wave-uniform base + lane*16
#define GLL(gsrc, ldst) \
  __builtin_amdgcn_global_load_lds((const __attribute__((address_space(1))) void*)(gsrc), \
                                   (__attribute__((address_space(3))) void*)(ldst), 16, 0, 0)

// ---------------------------------------------------------------------------
// K0: convert proj_w -> bf16; embed -> bf16*(-2); e_norm[k] = ||embed_k||^2
// ---------------------------------------------------------------------------
__global__ __launch_bounds__(256) void k_prep(const float* __restrict__ Wf,
                                              const float* __restrict__ Ef,
                                              unsigned short* __restrict__ Wbf,
                                              unsigned short* __restrict__ Ebf,
                                              float* __restrict__ e_norm) {
  int bid = blockIdx.x;
  if (bid < 512) {                      // W: 256*512 = 131072 elems
    int i = bid * 256 + threadIdx.x;
    Wbf[i] = f2bf(Wf[i]);
  } else if (bid < 1536) {              // E scaled by -2 (exact): 262144 elems
    int i = (bid - 512) * 256 + threadIdx.x;
    Ebf[i] = f2bf(-2.0f * Ef[i]);
  } else {                              // e_norm: 256 blocks * 4 codes (1 wave/code)
    int w = threadIdx.x >> 6, l = threadIdx.x & 63;
    int k = (bid - 1536) * 4 + w;
    const float4 v4 = ((const float4*)(Ef + (size_t)k * EF))[l];
    float s = v4.x * v4.x + v4.y * v4.y + v4.z * v4.z + v4.w * v4.w;
    for (int off = 32; off; off >>= 1) s += __shfl_down(s, off);
    if (l == 0) e_norm[k] = s;
  }
}

// ---------------------------------------------------------------------------
// K1 (fused), 512 threads / 128 tokens per block, 512 blocks:
//  phase1: x = in^T @ W^T. 8 waves: wave (tq=w&1, eq=w>>1) computes 64t x 64e,
//          acc[4][4]. A loaded transposed to regs (prefetch ks+1 during MFMA),
//          converted bf16 -> swizzled LDS. W via global_load_lds.
//  phase2: x += bias -> bf16 into xs[128][256] (swizzled); xsq += x^2.
//  phase3: wave (g=w&3: 32-token strip, h=w>>2: 16+16 codes). A-frags af[2][8]
//          LOADED ONCE into regs; then full 64 KB LDS = double-buffered es
//          (2 x 32KB, 64 codes/chunk, 16 chunks). Per chunk: GLL prefetch of
//          chunk+1, 32 MFMAs, ONE barrier. dist = ||e||^2 - 2 x.e via acc init
//          = e_norm (prefetched 1 chunk ahead) and Ebf pre-scaled by -2.
//  phase4: argmin merge (shfl16 -> LDS across wave-halves) -> bi, hist,
//          sse += sum(best_v) + sum(x^2).
// LDS 64 KB static. VGPR target <=128 (4 waves/SIMD -> 2 blocks/CU).
// ---------------------------------------------------------------------------
__global__ __launch_bounds__(512, 4) void k_fused(const float* __restrict__ in,
                                                  const unsigned short* __restrict__ Wbf,
                                                  const float* __restrict__ bias,
                                                  const unsigned short* __restrict__ Ebf,
                                                  const float* __restrict__ e_norm,
                                                  int* __restrict__ bi_out,
                                                  unsigned int* __restrict__ hist,
                                                  float* __restrict__ sse) {
  __shared__ unsigned short lds[32768];   // 64 KB
  unsigned short* as_ = lds;              // phase1 A [128 t][64 c]   16 KB
  unsigned short* bs  = lds + 8192;       // phase1 W [256 e][64 c]   32 KB
  unsigned short* xs  = lds;              // phase2   x [128 t][256 e] 64 KB

  int tid = threadIdx.x;
  int w = tid >> 6, l = tid & 63;
  int l15 = l & 15, quad = l >> 4;
  int tq = w & 1, eq = w >> 1;            // phase1 MFMA mapping
  int cg = w & 3, th = w >> 2;            // phase1 A-load mapping
  int tok0 = blockIdx.x * 128;
  const float* src = in + (size_t)(tok0 >> 12) * CIN * TT + (tok0 & 4095);

  // ------------------ phase 1: projection GEMM ------------------
  f32x4 acc[4][4];
#pragma unroll
  for (int a = 0; a < 4; ++a)
#pragma unroll
    for (int b = 0; b < 4; ++b) acc[a][b] = (f32x4){0.f, 0.f, 0.f, 0.f};

  float v[16];
  {
    const float* s0 = src + (size_t)(cg * 16) * TT + th * 64 + l;
#pragma unroll
    for (int i = 0; i < 16; ++i) v[i] = s0[(size_t)i * TT];
  }
  for (int ks = 0; ks < 8; ++ks) {
    int k0 = ks * 64;
    // W stage: 2048 16B chunks via GLL
#pragma unroll
    for (int i = 0; i < 4; ++i) {
      int g = i * 512 + tid;
      int row = g >> 3, pc = g & 7, lc = pc ^ (row & 7);
      GLL(Wbf + (size_t)row * CIN + k0 + lc * 8, bs + g * 8);
    }
    // A: convert current regs, swizzled b128 LDS writes
    int trow = th * 64 + l;
#pragma unroll
    for (int cc = 0; cc < 2; ++cc) {
      alignas(16) unsigned short tmp[8];
#pragma unroll
      for (int j = 0; j < 8; ++j) tmp[j] = f2bf(v[cc * 8 + j]);
      int c8 = cg * 2 + cc;
      int pc = c8 ^ (trow & 7);
      *(bf16x8*)(as_ + trow * 64 + pc * 8) = *(const bf16x8*)tmp;
    }
    __syncthreads();
    // prefetch next ks A (in flight across the MFMA window)
    if (ks < 7) {
      const float* s0 = src + (size_t)(k0 + 64 + cg * 16) * TT + th * 64 + l;
#pragma unroll
      for (int i = 0; i < 16; ++i) v[i] = s0[(size_t)i * TT];
    }
#pragma unroll
    for (int kstep = 0; kstep < 2; ++kstep) {
      int ck = kstep * 4 + quad;
      bf16x8 af[4], bfr[4];
#pragma unroll
      for (int msub = 0; msub < 4; ++msub) {
        int row = tq * 64 + msub * 16 + l15;
        int pa = ck ^ (row & 7);
        af[msub] = *(const bf16x8*)(as_ + row * 64 + pa * 8);
      }
#pragma unroll
      for (int nsub = 0; nsub < 4; ++nsub) {
        int row = eq * 64 + nsub * 16 + l15;
        int pb = ck ^ (row & 7);
        bfr[nsub] = *(const bf16x8*)(bs + row * 64 + pb * 8);
      }
#pragma unroll
      for (int msub = 0; msub < 4; ++msub)
#pragma unroll
        for (int nsub = 0; nsub < 4; ++nsub)
          acc[msub][nsub] = __builtin_amdgcn_mfma_f32_16x16x32_bf16(af[msub], bfr[nsub],
                                                                    acc[msub][nsub], 0, 0, 0);
    }
    __syncthreads();
  }

  // ------------------ phase 2: bias + x -> LDS xs, xsq ------------------
  float xsq = 0.f;
#pragma unroll
  for (int nsub = 0; nsub < 4; ++nsub) {
    int e = eq * 64 + nsub * 16 + l15;
    float bv = bias[e];
    int cx = e >> 3;
#pragma unroll
    for (int msub = 0; msub < 4; ++msub)
#pragma unroll
      for (int reg = 0; reg < 4; ++reg) {
        int m = tq * 64 + msub * 16 + quad * 4 + reg;
        float x = acc[msub][nsub][reg] + bv;
        xsq += x * x;
        int pcx = cx ^ (m & 31);
        xs[m * 256 + pcx * 8 + (e & 7)] = f2bf(x);
      }
  }
  __syncthreads();

  // ------------------ phase 3: A-frags to regs, then dbuf code stream ------
  int g3 = w & 3, h = w >> 2;
  bf16x8 af[2][8];
#pragma unroll
  for (int msub = 0; msub < 2; ++msub)
#pragma unroll
    for (int kst = 0; kst < 8; ++kst) {
      int row = g3 * 32 + msub * 16 + l15;
      int c32 = kst * 4 + quad;
      int pcx = c32 ^ (row & 31);
      af[msub][kst] = *(const bf16x8*)(xs + row * 256 + pcx * 8);
    }
  __syncthreads();   // xs dead; 64 KB free for es double-buffer

  // stage chunk 0 into buf 0
#pragma unroll
  for (int i = 0; i < 4; ++i) {
    int g = i * 512 + tid;
    int row = g >> 5, pcc = g & 31, lc = pcc ^ (row & 31);
    GLL(Ebf + (size_t)row * EF + lc * 8, lds + g * 8);
  }
  float enn[2];
  enn[0] = e_norm[h * 32 + l15];
  enn[1] = e_norm[h * 32 + 16 + l15];
  __syncthreads();

  float best_v[2][4];
  int best_i[2][4];
#pragma unroll
  for (int a = 0; a < 2; ++a)
#pragma unroll
    for (int b = 0; b < 4; ++b) { best_v[a][b] = 3.0e38f; best_i[a][b] = 0; }

  for (int chunk = 0; chunk < 16; ++chunk) {
    int p = chunk & 1;
    int c0 = chunk * 64;
    unsigned short* eb = lds + p * 16384;
    if (chunk < 15) {                       // prefetch chunk+1 into other buf
      unsigned short* ebn = lds + (p ^ 1) * 16384;
#pragma unroll
      for (int i = 0; i < 4; ++i) {
        int g = i * 512 + tid;
        int row = g >> 5, pcc = g & 31, lc = pcc ^ (row & 31);
        GLL(Ebf + (size_t)(c0 + 64 + row) * EF + lc * 8, ebn + g * 8);
      }
    }
    f32x4 dacc[2][2];
#pragma unroll
    for (int nsub = 0; nsub < 2; ++nsub) {
      float en = enn[nsub];
#pragma unroll
      for (int msub = 0; msub < 2; ++msub) dacc[msub][nsub] = (f32x4){en, en, en, en};
    }
    if (chunk < 15) {                       // prefetch next chunk's e_norm
      enn[0] = e_norm[c0 + 64 + h * 32 + l15];
      enn[1] = e_norm[c0 + 64 + h * 32 + 16 + l15];
    }
#pragma unroll
    for (int nsub = 0; nsub < 2; ++nsub) {
      int r = h * 32 + nsub * 16 + l15;
#pragma unroll
      for (int kst = 0; kst < 8; ++kst) {
        int cc = kst * 4 + quad;
        int pc = cc ^ (r & 31);
        bf16x8 bfr = *(const bf16x8*)(eb + r * 256 + pc * 8);
        dacc[0][nsub] = __builtin_amdgcn_mfma_f32_16x16x32_bf16(af[0][kst], bfr,
                                                                dacc[0][nsub], 0, 0, 0);
        dacc[1][nsub] = __builtin_amdgcn_mfma_f32_16x16x32_bf16(af[1][kst], bfr,
                                                                dacc[1][nsub], 0, 0, 0);
      }
    }
#pragma unroll
    for (int msub = 0; msub < 2; ++msub)
#pragma unroll
      for (int nsub = 0; nsub < 2; ++nsub) {
        int code = c0 + h * 32 + nsub * 16 + l15;
#pragma unroll
        for (int reg = 0; reg < 4; ++reg) {
          float vv = dacc[msub][nsub][reg];
          if (vv < best_v[msub][reg]) { best_v[msub][reg] = vv; best_i[msub][reg] = code; }
        }
      }
    __syncthreads();   // reads of eb done; GLL(chunk+1) drained
  }

  // ------------------ phase 4: argmin merge, outputs ------------------
#pragma unroll
  for (int msub = 0; msub < 2; ++msub)
#pragma unroll
    for (int reg = 0; reg < 4; ++reg) {
      float vv = best_v[msub][reg];
      int idx = best_i[msub][reg];
#pragma unroll
      for (int off = 8; off; off >>= 1) {
        float ov = __shfl_xor(vv, off, 16);
        int oi = __shfl_xor(idx, off, 16);
        if (ov < vv || (ov == vv && oi < idx)) { vv = ov; idx = oi; }
      }
      best_v[msub][reg] = vv;
      best_i[msub][reg] = idx;
    }
  float* red_v = (float*)lds;            // [2][128]  1 KB
  int* red_i = (int*)lds + 256;          // [2][128]  1 KB
  float* xred = (float*)lds + 512;       // [8]
  float* svred = (float*)lds + 520;      // [2]
  if (l15 == 0) {
#pragma unroll
    for (int msub = 0; msub < 2; ++msub)
#pragma unroll
      for (int reg = 0; reg < 4; ++reg) {
        int tokloc = g3 * 32 + msub * 16 + quad * 4 + reg;
        red_v[h * 128 + tokloc] = best_v[msub][reg];
        red_i[h * 128 + tokloc] = best_i[msub][reg];
      }
  }
  for (int off = 32; off; off >>= 1) xsq += __shfl_down(xsq, off);
  if (l == 0) xred[w] = xsq;
  __syncthreads();
  if (tid < 128) {
    float v0 = red_v[tid], v1 = red_v[128 + tid];
    int i0 = red_i[tid], i1 = red_i[128 + tid];
    float vv; int idx;
    if (v1 < v0 || (v1 == v0 && i1 < i0)) { vv = v1; idx = i1; } else { vv = v0; idx = i0; }
    bi_out[tok0 + tid] = idx;
    atomicAdd(&hist[idx], 1u);
    for (int off = 32; off; off >>= 1) vv += __shfl_down(vv, off);
    if ((tid & 63) == 0) svred[tid >> 6] = vv;
  }
  __syncthreads();
  if (tid == 0) {
    float tot = svred[0] + svred[1];
#pragma unroll
    for (int i = 0; i < 8; ++i) tot += xred[i];
    atomicAdd(sse, tot);
  }
}

// ---------------------------------------------------------------------------
// K2: gather embed rows (fp32 exact) by final index, write z_q transposed
// [B][EF][TT]. Tile: 128 tokens x 64 e. LDS [t][e] stride 65.
// ---------------------------------------------------------------------------
__global__ __launch_bounds__(256) void k_gather(const float* __restrict__ embed,
                                                const int* __restrict__ bi,
                                                float* __restrict__ out) {
  __shared__ float zq[128 * 65];
  __shared__ int idxs[128];
  int tid = threadIdx.x;
  int tok0 = blockIdx.x * 128;
  int e0 = blockIdx.y * 64;
  if (tid < 128) idxs[tid] = bi[tok0 + tid];
  __syncthreads();
  int l15 = tid & 15, tg = tid >> 4;   // 16 thread-groups of 16 lanes
  for (int r = 0; r < 8; ++r) {
    int tl = r * 16 + tg;
    const float4 v = *(const float4*)(embed + (size_t)idxs[tl] * EF + e0 + l15 * 4);
    float* zr = zq + tl * 65 + l15 * 4;
    zr[0] = v.x; zr[1] = v.y; zr[2] = v.z; zr[3] = v.w;
  }
  __syncthreads();
  int b = tok0 >> 12, t0 = tok0 & 4095;
  int tl4 = (tid & 31) * 4;
  for (int r = 0; r < 8; ++r) {
    int e = r * 8 + (tid >> 5);
    float4 v;
    v.x = zq[(tl4 + 0) * 65 + e];
    v.y = zq[(tl4 + 1) * 65 + e];
    v.z = zq[(tl4 + 2) * 65 + e];
    v.w = zq[(tl4 + 3) * 65 + e];
    *(float4*)(out + ((size_t)(b * EF + e0 + e) << 12) + t0 + tl4) = v;
  }
}

// ---------------------------------------------------------------------------
// K3: finalize scalars
// ---------------------------------------------------------------------------
__global__ __launch_bounds__(256) void k_final(const unsigned int* __restrict__ hist,
                                               const float* __restrict__ sse,
                                               float* __restrict__ out) {
  __shared__ float red[4];
  int tid = threadIdx.x;
  float local = 0.f;
  for (int i = tid; i < NE; i += 256) {
    float p = (float)hist[i] * (1.0f / 65536.0f);
    local -= p * logf(p + 1e-10f);
  }
  for (int off = 32; off; off >>= 1) local += __shfl_down(local, off);
  if ((tid & 63) == 0) red[tid >> 6] = local;
  __syncthreads();
  if (tid == 0) {
    float lp = red[0] + red[1] + red[2] + red[3];
    out[16777216] = 1.25f * sse[0] / 16777216.0f;  // vq + 0.25*commitment
    out[16777233] = lp;
  }
  if (tid < 16) out[16777217 + tid] = 6.93147180559945f * 4096.0f;  // log(1024)*4096
}

// ---------------------------------------------------------------------------
extern "C" void kernel_launch(void* const* d_in, const int* in_sizes, int n_in,
                              void* d_out, int out_size, void* d_ws, size_t ws_size,
                              hipStream_t stream) {
  const float* inputs = (const float*)d_in[0];
  const float* proj_w = (const float*)d_in[1];
  const float* proj_b = (const float*)d_in[2];
  const float* embed = (const float*)d_in[3];
  float* out = (float*)d_out;
  char* ws = (char*)d_ws;

  // workspace layout
  unsigned short* Wbf  = (unsigned short*)(ws);            //   262,144 B
  unsigned short* Ebf  = (unsigned short*)(ws + 262144);   //   524,288 B
  float* e_norm        = (float*)(ws + 786432);            //     4,096 B
  int* bi              = (int*)(ws + 790528);              //   262,144 B
  unsigned int* hist   = (unsigned int*)(ws + 1052672);    //     4,096 B
  float* sse           = (float*)(ws + 1056768);           //         4 B
  if (ws_size < 1056772) return;

  hipMemsetAsync(ws + 1052672, 0, 4100, stream);  // hist + sse

  k_prep<<<1792, 256, 0, stream>>>(proj_w, embed, Wbf, Ebf, e_norm);
  k_fused<<<512, 512, 0, stream>>>(inputs, Wbf, proj_b, Ebf, e_norm, bi, hist, sse);
  k_gather<<<dim3(512, 4), 256, 0, stream>>>(embed, bi, out);
  k_final<<<1, 256, 0, stream>>>(hist, sse, out);
}

// Round 5
// 295.724 us; speedup vs baseline: 1.1267x; 1.1066x over previous
//
#include <hip/hip_runtime.h>
#include <hip/hip_bf16.h>
#include <math.h>

// Problem constants
#define TT   4096     // T
#define BB   16       // B
#define NTOK 65536    // B*T
#define CIN  512      // IN_FEATS
#define EF   256      // EMBED_FEATS
#define NE   1024     // NUM_EMBED

typedef __attribute__((ext_vector_type(8))) short bf16x8;
typedef __attribute__((ext_vector_type(4))) float f32x4;

static __device__ __forceinline__ unsigned short f2bf(float f) {
  unsigned int u = __float_as_uint(f);
  u += 0x7fffu + ((u >> 16) & 1u);          // RNE
  return (unsigned short)(u >> 16);
}

// async global->LDS, 16B per lane; LDS dest is wave-uniform base + lane*16
#define GLL(gsrc, ldst) \
  __builtin_amdgcn_global_load_lds((const __attribute__((address_space(1))) void*)(gsrc), \
                                   (__attribute__((address_space(3))) void*)(ldst), 16, 0, 0)

// ---------------------------------------------------------------------------
// K0: convert proj_w -> bf16; embed -> bf16*(-2); e_norm[k] = ||embed_k||^2
// ---------------------------------------------------------------------------
__global__ __launch_bounds__(256) void k_prep(const float* __restrict__ Wf,
                                              const float* __restrict__ Ef,
                                              unsigned short* __restrict__ Wbf,
                                              unsigned short* __restrict__ Ebf,
                                              float* __restrict__ e_norm) {
  int bid = blockIdx.x;
  if (bid < 512) {                      // W: 256*512 = 131072 elems
    int i = bid * 256 + threadIdx.x;
    Wbf[i] = f2bf(Wf[i]);
  } else if (bid < 1536) {              // E scaled by -2 (exact): 262144 elems
    int i = (bid - 512) * 256 + threadIdx.x;
    Ebf[i] = f2bf(-2.0f * Ef[i]);
  } else {                              // e_norm: 256 blocks * 4 codes (1 wave/code)
    int w = threadIdx.x >> 6, l = threadIdx.x & 63;
    int k = (bid - 1536) * 4 + w;
    const float4 v4 = ((const float4*)(Ef + (size_t)k * EF))[l];
    float s = v4.x * v4.x + v4.y * v4.y + v4.z * v4.z + v4.w * v4.w;
    for (int off = 32; off; off >>= 1) s += __shfl_down(s, off);
    if (l == 0) e_norm[k] = s;
  }
}

// ---------------------------------------------------------------------------
// K1 (fused), 512 threads / 128 tokens per block, 512 blocks.
// NOTE launch_bounds: this compiler effectively gives VGPR = 512 / (arg *
// waves_per_block / 4) for 512-thread blocks: arg=2 -> 128 VGPR (measured R1),
// arg=4 -> 64 VGPR + catastrophic spills (measured R4). KEEP arg=2.
//  phase1: x = in^T @ W^T. 8 waves: wave (tq=w&1, eq=w>>1) computes 64t x 64e,
//          acc[4][4]. A loaded transposed to regs (prefetch ks+1 during MFMA),
//          converted bf16 -> swizzled LDS. W via global_load_lds.
//  phase2: x += bias -> bf16 into xs[128][256] (swizzled); xsq += x^2.
//  phase3: wave (g=w&3: 32-token strip, h=w>>2: 16+16 codes). A-frags af[2][8]
//          LOADED ONCE into regs; then full 64 KB LDS = double-buffered es
//          (2 x 32KB, 64 codes/chunk, 16 chunks). Per chunk: GLL prefetch of
//          chunk+1, 32 MFMAs, ONE barrier. dist = ||e||^2 - 2 x.e via acc init
//          = e_norm (prefetched 1 chunk ahead) and Ebf pre-scaled by -2.
//  phase4: argmin merge (shfl16 -> LDS across wave-halves) -> bi, hist,
//          sse += sum(best_v) + sum(x^2).
// LDS 64 KB static -> 2 blocks/CU; VGPR 128 -> no spills.
// ---------------------------------------------------------------------------
__global__ __launch_bounds__(512, 2) void k_fused(const float* __restrict__ in,
                                                  const unsigned short* __restrict__ Wbf,
                                                  const float* __restrict__ bias,
                                                  const unsigned short* __restrict__ Ebf,
                                                  const float* __restrict__ e_norm,
                                                  int* __restrict__ bi_out,
                                                  unsigned int* __restrict__ hist,
                                                  float* __restrict__ sse) {
  __shared__ unsigned short lds[32768];   // 64 KB
  unsigned short* as_ = lds;              // phase1 A [128 t][64 c]   16 KB
  unsigned short* bs  = lds + 8192;       // phase1 W [256 e][64 c]   32 KB
  unsigned short* xs  = lds;              // phase2   x [128 t][256 e] 64 KB

  int tid = threadIdx.x;
  int w = tid >> 6, l = tid & 63;
  int l15 = l & 15, quad = l >> 4;
  int tq = w & 1, eq = w >> 1;            // phase1 MFMA mapping
  int cg = w & 3, th = w >> 2;            // phase1 A-load mapping
  int tok0 = blockIdx.x * 128;
  const float* src = in + (size_t)(tok0 >> 12) * CIN * TT + (tok0 & 4095);

  // ------------------ phase 1: projection GEMM ------------------
  f32x4 acc[4][4];
#pragma unroll
  for (int a = 0; a < 4; ++a)
#pragma unroll
    for (int b = 0; b < 4; ++b) acc[a][b] = (f32x4){0.f, 0.f, 0.f, 0.f};

  float v[16];
  {
    const float* s0 = src + (size_t)(cg * 16) * TT + th * 64 + l;
#pragma unroll
    for (int i = 0; i < 16; ++i) v[i] = s0[(size_t)i * TT];
  }
  for (int ks = 0; ks < 8; ++ks) {
    int k0 = ks * 64;
    // W stage: 2048 16B chunks via GLL
#pragma unroll
    for (int i = 0; i < 4; ++i) {
      int g = i * 512 + tid;
      int row = g >> 3, pc = g & 7, lc = pc ^ (row & 7);
      GLL(Wbf + (size_t)row * CIN + k0 + lc * 8, bs + g * 8);
    }
    // A: convert current regs, swizzled b128 LDS writes
    int trow = th * 64 + l;
#pragma unroll
    for (int cc = 0; cc < 2; ++cc) {
      alignas(16) unsigned short tmp[8];
#pragma unroll
      for (int j = 0; j < 8; ++j) tmp[j] = f2bf(v[cc * 8 + j]);
      int c8 = cg * 2 + cc;
      int pc = c8 ^ (trow & 7);
      *(bf16x8*)(as_ + trow * 64 + pc * 8) = *(const bf16x8*)tmp;
    }
    __syncthreads();
    // prefetch next ks A (in flight across the MFMA window)
    if (ks < 7) {
      const float* s0 = src + (size_t)(k0 + 64 + cg * 16) * TT + th * 64 + l;
#pragma unroll
      for (int i = 0; i < 16; ++i) v[i] = s0[(size_t)i * TT];
    }
#pragma unroll
    for (int kstep = 0; kstep < 2; ++kstep) {
      int ck = kstep * 4 + quad;
      bf16x8 af[4], bfr[4];
#pragma unroll
      for (int msub = 0; msub < 4; ++msub) {
        int row = tq * 64 + msub * 16 + l15;
        int pa = ck ^ (row & 7);
        af[msub] = *(const bf16x8*)(as_ + row * 64 + pa * 8);
      }
#pragma unroll
      for (int nsub = 0; nsub < 4; ++nsub) {
        int row = eq * 64 + nsub * 16 + l15;
        int pb = ck ^ (row & 7);
        bfr[nsub] = *(const bf16x8*)(bs + row * 64 + pb * 8);
      }
#pragma unroll
      for (int msub = 0; msub < 4; ++msub)
#pragma unroll
        for (int nsub = 0; nsub < 4; ++nsub)
          acc[msub][nsub] = __builtin_amdgcn_mfma_f32_16x16x32_bf16(af[msub], bfr[nsub],
                                                                    acc[msub][nsub], 0, 0, 0);
    }
    __syncthreads();
  }

  // ------------------ phase 2: bias + x -> LDS xs, xsq ------------------
  float xsq = 0.f;
#pragma unroll
  for (int nsub = 0; nsub < 4; ++nsub) {
    int e = eq * 64 + nsub * 16 + l15;
    float bv = bias[e];
    int cx = e >> 3;
#pragma unroll
    for (int msub = 0; msub < 4; ++msub)
#pragma unroll
      for (int reg = 0; reg < 4; ++reg) {
        int m = tq * 64 + msub * 16 + quad * 4 + reg;
        float x = acc[msub][nsub][reg] + bv;
        xsq += x * x;
        int pcx = cx ^ (m & 31);
        xs[m * 256 + pcx * 8 + (e & 7)] = f2bf(x);
      }
  }
  __syncthreads();

  // ------------------ phase 3: A-frags to regs, then dbuf code stream ------
  int g3 = w & 3, h = w >> 2;
  bf16x8 af[2][8];
#pragma unroll
  for (int msub = 0; msub < 2; ++msub)
#pragma unroll
    for (int kst = 0; kst < 8; ++kst) {
      int row = g3 * 32 + msub * 16 + l15;
      int c32 = kst * 4 + quad;
      int pcx = c32 ^ (row & 31);
      af[msub][kst] = *(const bf16x8*)(xs + row * 256 + pcx * 8);
    }
  __syncthreads();   // xs dead; 64 KB free for es double-buffer

  // stage chunk 0 into buf 0
#pragma unroll
  for (int i = 0; i < 4; ++i) {
    int g = i * 512 + tid;
    int row = g >> 5, pcc = g & 31, lc = pcc ^ (row & 31);
    GLL(Ebf + (size_t)row * EF + lc * 8, lds + g * 8);
  }
  float enn[2];
  enn[0] = e_norm[h * 32 + l15];
  enn[1] = e_norm[h * 32 + 16 + l15];
  __syncthreads();

  float best_v[2][4];
  int best_i[2][4];
#pragma unroll
  for (int a = 0; a < 2; ++a)
#pragma unroll
    for (int b = 0; b < 4; ++b) { best_v[a][b] = 3.0e38f; best_i[a][b] = 0; }

  for (int chunk = 0; chunk < 16; ++chunk) {
    int p = chunk & 1;
    int c0 = chunk * 64;
    unsigned short* eb = lds + p * 16384;
    if (chunk < 15) {                       // prefetch chunk+1 into other buf
      unsigned short* ebn = lds + (p ^ 1) * 16384;
#pragma unroll
      for (int i = 0; i < 4; ++i) {
        int g = i * 512 + tid;
        int row = g >> 5, pcc = g & 31, lc = pcc ^ (row & 31);
        GLL(Ebf + (size_t)(c0 + 64 + row) * EF + lc * 8, ebn + g * 8);
      }
    }
    f32x4 dacc[2][2];
#pragma unroll
    for (int nsub = 0; nsub < 2; ++nsub) {
      float en = enn[nsub];
#pragma unroll
      for (int msub = 0; msub < 2; ++msub) dacc[msub][nsub] = (f32x4){en, en, en, en};
    }
    if (chunk < 15) {                       // prefetch next chunk's e_norm
      enn[0] = e_norm[c0 + 64 + h * 32 + l15];
      enn[1] = e_norm[c0 + 64 + h * 32 + 16 + l15];
    }
#pragma unroll
    for (int nsub = 0; nsub < 2; ++nsub) {
      int r = h * 32 + nsub * 16 + l15;
#pragma unroll
      for (int kst = 0; kst < 8; ++kst) {
        int cc = kst * 4 + quad;
        int pc = cc ^ (r & 31);
        bf16x8 bfr = *(const bf16x8*)(eb + r * 256 + pc * 8);
        dacc[0][nsub] = __builtin_amdgcn_mfma_f32_16x16x32_bf16(af[0][kst], bfr,
                                                                dacc[0][nsub], 0, 0, 0);
        dacc[1][nsub] = __builtin_amdgcn_mfma_f32_16x16x32_bf16(af[1][kst], bfr,
                                                                dacc[1][nsub], 0, 0, 0);
      }
    }
#pragma unroll
    for (int msub = 0; msub < 2; ++msub)
#pragma unroll
      for (int nsub = 0; nsub < 2; ++nsub) {
        int code = c0 + h * 32 + nsub * 16 + l15;
#pragma unroll
        for (int reg = 0; reg < 4; ++reg) {
          float vv = dacc[msub][nsub][reg];
          if (vv < best_v[msub][reg]) { best_v[msub][reg] = vv; best_i[msub][reg] = code; }
        }
      }
    __syncthreads();   // reads of eb done; GLL(chunk+1) drained
  }

  // ------------------ phase 4: argmin merge, outputs ------------------
#pragma unroll
  for (int msub = 0; msub < 2; ++msub)
#pragma unroll
    for (int reg = 0; reg < 4; ++reg) {
      float vv = best_v[msub][reg];
      int idx = best_i[msub][reg];
#pragma unroll
      for (int off = 8; off; off >>= 1) {
        float ov = __shfl_xor(vv, off, 16);
        int oi = __shfl_xor(idx, off, 16);
        if (ov < vv || (ov == vv && oi < idx)) { vv = ov; idx = oi; }
      }
      best_v[msub][reg] = vv;
      best_i[msub][reg] = idx;
    }
  float* red_v = (float*)lds;            // [2][128]  1 KB
  int* red_i = (int*)lds + 256;          // [2][128]  1 KB
  float* xred = (float*)lds + 512;       // [8]
  float* svred = (float*)lds + 520;      // [2]
  if (l15 == 0) {
#pragma unroll
    for (int msub = 0; msub < 2; ++msub)
#pragma unroll
      for (int reg = 0; reg < 4; ++reg) {
        int tokloc = g3 * 32 + msub * 16 + quad * 4 + reg;
        red_v[h * 128 + tokloc] = best_v[msub][reg];
        red_i[h * 128 + tokloc] = best_i[msub][reg];
      }
  }
  for (int off = 32; off; off >>= 1) xsq += __shfl_down(xsq, off);
  if (l == 0) xred[w] = xsq;
  __syncthreads();
  if (tid < 128) {
    float v0 = red_v[tid], v1 = red_v[128 + tid];
    int i0 = red_i[tid], i1 = red_i[128 + tid];
    float vv; int idx;
    if (v1 < v0 || (v1 == v0 && i1 < i0)) { vv = v1; idx = i1; } else { vv = v0; idx = i0; }
    bi_out[tok0 + tid] = idx;
    atomicAdd(&hist[idx], 1u);
    for (int off = 32; off; off >>= 1) vv += __shfl_down(vv, off);
    if ((tid & 63) == 0) svred[tid >> 6] = vv;
  }
  __syncthreads();
  if (tid == 0) {
    float tot = svred[0] + svred[1];
#pragma unroll
    for (int i = 0; i < 8; ++i) tot += xred[i];
    atomicAdd(sse, tot);
  }
}

// ---------------------------------------------------------------------------
// K2: gather embed rows (fp32 exact) by final index, write z_q transposed
// [B][EF][TT]. Tile: 128 tokens x 64 e. LDS [t][e] stride 65.
// ---------------------------------------------------------------------------
__global__ __launch_bounds__(256) void k_gather(const float* __restrict__ embed,
                                                const int* __restrict__ bi,
                                                float* __restrict__ out) {
  __shared__ float zq[128 * 65];
  __shared__ int idxs[128];
  int tid = threadIdx.x;
  int tok0 = blockIdx.x * 128;
  int e0 = blockIdx.y * 64;
  if (tid < 128) idxs[tid] = bi[tok0 + tid];
  __syncthreads();
  int l15 = tid & 15, tg = tid >> 4;   // 16 thread-groups of 16 lanes
  for (int r = 0; r < 8; ++r) {
    int tl = r * 16 + tg;
    const float4 v = *(const float4*)(embed + (size_t)idxs[tl] * EF + e0 + l15 * 4);
    float* zr = zq + tl * 65 + l15 * 4;
    zr[0] = v.x; zr[1] = v.y; zr[2] = v.z; zr[3] = v.w;
  }
  __syncthreads();
  int b = tok0 >> 12, t0 = tok0 & 4095;
  int tl4 = (tid & 31) * 4;
  for (int r = 0; r < 8; ++r) {
    int e = r * 8 + (tid >> 5);
    float4 v;
    v.x = zq[(tl4 + 0) * 65 + e];
    v.y = zq[(tl4 + 1) * 65 + e];
    v.z = zq[(tl4 + 2) * 65 + e];
    v.w = zq[(tl4 + 3) * 65 + e];
    *(float4*)(out + ((size_t)(b * EF + e0 + e) << 12) + t0 + tl4) = v;
  }
}

// ---------------------------------------------------------------------------
// K3: finalize scalars
// ---------------------------------------------------------------------------
__global__ __launch_bounds__(256) void k_final(const unsigned int* __restrict__ hist,
                                               const float* __restrict__ sse,
                                               float* __restrict__ out) {
  __shared__ float red[4];
  int tid = threadIdx.x;
  float local = 0.f;
  for (int i = tid; i < NE; i += 256) {
    float p = (float)hist[i] * (1.0f / 65536.0f);
    local -= p * logf(p + 1e-10f);
  }
  for (int off = 32; off; off >>= 1) local += __shfl_down(local, off);
  if ((tid & 63) == 0) red[tid >> 6] = local;
  __syncthreads();
  if (tid == 0) {
    float lp = red[0] + red[1] + red[2] + red[3];
    out[16777216] = 1.25f * sse[0] / 16777216.0f;  // vq + 0.25*commitment
    out[16777233] = lp;
  }
  if (tid < 16) out[16777217 + tid] = 6.93147180559945f * 4096.0f;  // log(1024)*4096
}

// ---------------------------------------------------------------------------
extern "C" void kernel_launch(void* const* d_in, const int* in_sizes, int n_in,
                              void* d_out, int out_size, void* d_ws, size_t ws_size,
                              hipStream_t stream) {
  const float* inputs = (const float*)d_in[0];
  const float* proj_w = (const float*)d_in[1];
  const float* proj_b = (const float*)d_in[2];
  const float* embed = (const float*)d_in[3];
  float* out = (float*)d_out;
  char* ws = (char*)d_ws;

  // workspace layout
  unsigned short* Wbf  = (unsigned short*)(ws);            //   262,144 B
  unsigned short* Ebf  = (unsigned short*)(ws + 262144);   //   524,288 B
  float* e_norm        = (float*)(ws + 786432);            //     4,096 B
  int* bi              = (int*)(ws + 790528);              //   262,144 B
  unsigned int* hist   = (unsigned int*)(ws + 1052672);    //     4,096 B
  float* sse           = (float*)(ws + 1056768);           //         4 B
  if (ws_size < 1056772) return;

  hipMemsetAsync(ws + 1052672, 0, 4100, stream);  // hist + sse

  k_prep<<<1792, 256, 0, stream>>>(proj_w, embed, Wbf, Ebf, e_norm);
  k_fused<<<512, 512, 0, stream>>>(inputs, Wbf, proj_b, Ebf, e_norm, bi, hist, sse);
  k_gather<<<dim3(512, 4), 256, 0, stream>>>(embed, bi, out);
  k_final<<<1, 256, 0, stream>>>(hist, sse, out);
}